// Round 11
// baseline (118.654 us; speedup 1.0000x reference)
//
#include <hip/hip_runtime.h>
#include <math.h>

#define PI_F        3.14159265358979323846f
#define TWO_PI_F    6.2831853071795864769f
#define INV_TWO_PI_F 0.15915494309189533577f

typedef __attribute__((ext_vector_type(8))) short  bf16x8;
typedef __attribute__((ext_vector_type(8))) __bf16 bf16v8;
typedef __attribute__((ext_vector_type(4))) float  f32x4;

__device__ __forceinline__ bf16x8 cvt8(f32x4 a, f32x4 b) {
    bf16v8 v;
    v[0] = (__bf16)a.x; v[1] = (__bf16)a.y; v[2] = (__bf16)a.z; v[3] = (__bf16)a.w;
    v[4] = (__bf16)b.x; v[5] = (__bf16)b.y; v[6] = (__bf16)b.z; v[7] = (__bf16)b.w;
    return __builtin_bit_cast(bf16x8, v);
}

// ------------------------------------------------------------------
// W prep: convert W (f32 [64][256]) into bf16 MFMA B-fragment layout:
// wfb[level][(nt4*8+ks)*64 + lane] = W[nt4*16+(l&15)][ks*32+(l>>4)*8 ..+8]
// (nt4 = global 16-col tile 0..3). One 16B fragment per thread.
// ------------------------------------------------------------------
__global__ __launch_bounds__(256) void wprep(
    const float* __restrict__ W0, const float* __restrict__ W1,
    const float* __restrict__ W2, __bf16* __restrict__ wfb)
{
    const int level = blockIdx.x >> 3;
    const int rem   = ((blockIdx.x & 7) << 8) | threadIdx.x;   // 0..2047
    const float* W  = level == 0 ? W0 : (level == 1 ? W1 : W2);
    const int l   = rem & 63;
    const int ks  = (rem >> 6) & 7;
    const int nt4 = rem >> 9;
    const int col = nt4 * 16 + (l & 15);
    const int k0  = ks * 32 + (l >> 4) * 8;
    const float* wp = W + col * 256 + k0;
    bf16x8 f = cvt8(*(const f32x4*)wp, *(const f32x4*)(wp + 4));
    *(bf16x8*)(wfb + (size_t)level * 16384 + (size_t)rem * 8) = f;
}

// ------------------------------------------------------------------
// Register-direct bf16-MFMA GEMM with FORCED memory-level parallelism:
// y = x (.) W^T, K=256, Do=64, y stored bf16.
// 256 thr = 4 waves (2 row x 2 col halves); each wave independently does
// 16 rows x 32 cols:
//   1) issue 16 W-frag loads + ALL 16 A-loads (f32x4, named registers)
//   2) sched_barrier(0)  -- hard fence: every load is in flight before
//      any use; the allocator must keep ~155 VGPRs live (16KB/wave MLP)
//   3) cvt f32->bf16 + 16 MFMA (2 acc chains), store.
// No LDS, no barriers, no DMA. 12 waves/CU x 16KB = ~192KB in flight/CU.
// MFMA 16x16x32: A(m,k): lane=(k>>3)*16+m, slots k&7.
//                B(k,n): lane=(k>>3)*16+n.
//                C(m,n): n=lane&15, m=(lane>>4)*4+reg.
// ------------------------------------------------------------------
__device__ __forceinline__ void gemm_body(
    int bid,
    const float* __restrict__ x, const __bf16* __restrict__ wfb,
    __bf16* __restrict__ y)
{
    const int tid  = threadIdx.x;
    const int lane = tid & 63;
    const int w    = tid >> 6;
    const int wm   = w >> 1;                 // row half (16 rows)
    const int wn   = w & 1;                  // col half (32 cols)
    const int l16  = lane & 15;
    const int lq   = lane >> 4;
    const long r0  = (long)bid * 32 + wm * 16;

    // ---- issue W-frag loads (L2-resident after first blocks)
    bf16x8 wf[2][8];
    #pragma unroll
    for (int nt = 0; nt < 2; ++nt) {
        const __bf16* wb = wfb + (size_t)(wn * 2 + nt) * 4096 + (size_t)lane * 8;
        #pragma unroll
        for (int ks = 0; ks < 8; ++ks)
            wf[nt][ks] = *(const bf16x8*)(wb + ks * 512);
    }

    // ---- issue ALL 16 A-loads into named registers (full-line coalesced:
    // lanes {m,m+16,m+32,m+48} cover row m's 128B k-span)
    f32x4 xa[8], xb[8];
    const float* xr = x + (r0 + l16) * 256 + lq * 8;
    #pragma unroll
    for (int ks = 0; ks < 8; ++ks) {
        xa[ks] = *(const f32x4*)(xr + ks * 32);
        xb[ks] = *(const f32x4*)(xr + ks * 32 + 4);
    }

    __builtin_amdgcn_sched_barrier(0);   // fence: loads above, compute below

    f32x4 acc0 = {0.f, 0.f, 0.f, 0.f};
    f32x4 acc1 = {0.f, 0.f, 0.f, 0.f};
    #pragma unroll
    for (int ks = 0; ks < 8; ++ks) {
        bf16x8 a = cvt8(xa[ks], xb[ks]);
        acc0 = __builtin_amdgcn_mfma_f32_16x16x32_bf16(a, wf[0][ks], acc0, 0, 0, 0);
        acc1 = __builtin_amdgcn_mfma_f32_16x16x32_bf16(a, wf[1][ks], acc1, 0, 0, 0);
    }

    // ---- store: C(m,n): n = lane&15, m = (lane>>4)*4 + j; bf16
    const long rr  = r0 + lq * 4;
    const int col0 = wn * 32 + l16;
    #pragma unroll
    for (int j = 0; j < 4; ++j) {
        y[(rr + j) * 64 + col0]      = (__bf16)acc0[j];
        y[(rr + j) * 64 + col0 + 16] = (__bf16)acc1[j];
    }
}

// Fused GEMM: blocks [0,4096) L0, [4096,5120) L1, [5120,5376) L2 (32-row blocks)
__global__ __launch_bounds__(256, 3) void gemm_fused(
    const float* __restrict__ x0, const float* __restrict__ x1,
    const float* __restrict__ x2,
    const __bf16* __restrict__ wfb,
    __bf16* __restrict__ y0, __bf16* __restrict__ y1, __bf16* __restrict__ y2)
{
    const int b = blockIdx.x;
    if (b < 4096)       gemm_body(b,        x0, wfb,         y0);
    else if (b < 5120)  gemm_body(b - 4096, x1, wfb + 16384, y1);
    else                gemm_body(b - 5120, x2, wfb + 32768, y2);
}

// ------------------------------------------------------------------
// Projection body: per group g, neighbors nh[g][0..7]:
//   logw[p][j] = -(dlat^2+dlon_w^2)/(2 sigma^2) + kappa*(cos(dlon_w)-1)
//   w = softmax_j(logw);  out[n=g*GS+p][d] = sum_j w[p][j]*y[nh[g][j]][d]
// ------------------------------------------------------------------
template<int GS, int CG, int ROUNDS>
__device__ __forceinline__ void proj_body(
    int bid, float (*wlds)[128],
    const __bf16* __restrict__ y,      // [B*N][64] bf16
    const float* __restrict__ coords,  // [2][N]
    const int*   __restrict__ nh,      // [N][8]
    const float* __restrict__ oc,      // [2][B][N0]
    const float* __restrict__ sig_p,
    const float* __restrict__ kap_p,
    float* __restrict__ out,           // [B][N0][64]
    int N, int N0)
{
    constexpr int B = 2;
    static_assert(CG * GS == ROUNDS * 8, "slot layout");

    const int wslot = threadIdx.x >> 6;
    const int lane  = threadIdx.x & 63;
    const int wave  = (bid << 2) + wslot;
    const int gpb   = N / CG;
    const int b     = wave / gpb;
    const int g0    = (wave - b * gpb) * CG;

    const float sigma  = *sig_p;
    const float kappa  = *kap_p;
    const float inv2s2 = 1.0f / (2.0f * sigma * sigma);

    const int j  = lane & 7;
    const int pp = lane >> 3;

    #pragma unroll
    for (int r = 0; r < ROUNDS; ++r) {
        const int pidx = r * 8 + pp;
        const int q = pidx / GS;
        const int p = pidx - q * GS;
        const int g = g0 + q;
        const int idx = nh[g * 8 + j];
        const float clon = coords[idx];
        const float clat = coords[N + idx];
        const int n = g * GS + p;
        const float olon = oc[(long)b * N0 + n];
        const float olat = oc[(long)(B + b) * N0 + n];

        float dlon = olon - clon;
        float t = (dlon + PI_F) * INV_TWO_PI_F;   // floor-mod wrap to [-pi, pi)
        t -= floorf(t);
        dlon = t * TWO_PI_F - PI_F;
        const float dlat = olat - clat;

        float logw = -(dlat * dlat + dlon * dlon) * inv2s2
                   + kappa * (cosf(dlon) - 1.0f);

        float m = logw;
        m = fmaxf(m, __shfl_xor(m, 1));
        m = fmaxf(m, __shfl_xor(m, 2));
        m = fmaxf(m, __shfl_xor(m, 4));
        float e = expf(logw - m);
        float s = e;
        s += __shfl_xor(s, 1);
        s += __shfl_xor(s, 2);
        s += __shfl_xor(s, 4);
        wlds[wslot][r * 64 + lane] = e / s;
    }

    __syncthreads();

    const int d = lane;
    const __bf16* yb = y + (long)b * N * 64 + d;
    #pragma unroll
    for (int pidx = 0; pidx < CG * GS; ++pidx) {
        const int q = pidx / GS;
        const int p = pidx - q * GS;
        const int g = g0 + q;
        const int* nhg = nh + g * 8;
        const float* wrow = &wlds[wslot][(pidx >> 3) * 64 + (pidx & 7) * 8];
        float a = 0.0f;
        #pragma unroll
        for (int jj = 0; jj < 8; ++jj)
            a = fmaf(wrow[jj], (float)yb[(long)nhg[jj] * 64], a);
        const int n = g * GS + p;
        out[((long)b * N0 + n) * 64 + d] = a;
    }
}

// Fused projection: blocks [0,4096) L0, [4096,8192) L1, [8192,10240) L2.
__global__ __launch_bounds__(256) void proj_fused(
    const __bf16* __restrict__ y0, const __bf16* __restrict__ y1,
    const __bf16* __restrict__ y2,
    const float* __restrict__ c0, const float* __restrict__ c1,
    const float* __restrict__ c2,
    const int* __restrict__ nh0, const int* __restrict__ nh1,
    const int* __restrict__ nh2,
    const float* __restrict__ oc,
    const float* __restrict__ sig0, const float* __restrict__ sig1,
    const float* __restrict__ sig2,
    const float* __restrict__ kap0, const float* __restrict__ kap1,
    const float* __restrict__ kap2,
    float* __restrict__ out)
{
    __shared__ float wlds[4][128];
    const size_t SLICE = (size_t)2 * 65536 * 64;
    const int b = blockIdx.x;
    if (b < 4096)
        proj_body<1, 8, 1>(b, wlds, y0, c0, nh0, oc, sig0, kap0,
                           out, 65536, 65536);
    else if (b < 8192)
        proj_body<4, 2, 1>(b - 4096, wlds, y1, c1, nh1, oc, sig1, kap1,
                           out + SLICE, 16384, 65536);
    else
        proj_body<16, 1, 2>(b - 8192, wlds, y2, c2, nh2, oc, sig2, kap2,
                            out + 2 * SLICE, 4096, 65536);
}

// ------------------------------------------------------------------
extern "C" void kernel_launch(void* const* d_in, const int* in_sizes, int n_in,
                              void* d_out, int out_size, void* d_ws, size_t ws_size,
                              hipStream_t stream)
{
    const float* x0   = (const float*)d_in[0];
    const float* x1   = (const float*)d_in[1];
    const float* x2   = (const float*)d_in[2];
    const float* W0   = (const float*)d_in[3];
    const float* W1   = (const float*)d_in[4];
    const float* W2   = (const float*)d_in[5];
    const float* sig0 = (const float*)d_in[6];
    const float* sig1 = (const float*)d_in[7];
    const float* sig2 = (const float*)d_in[8];
    const float* kap0 = (const float*)d_in[9];
    const float* kap1 = (const float*)d_in[10];
    const float* kap2 = (const float*)d_in[11];
    const float* c0   = (const float*)d_in[12];
    const float* c1   = (const float*)d_in[13];
    const float* c2   = (const float*)d_in[14];
    const int*   nh0  = (const int*)d_in[15];
    const int*   nh1  = (const int*)d_in[16];
    const int*   nh2  = (const int*)d_in[17];
    const float* oc   = (const float*)d_in[18];

    float* out = (float*)d_out;
    // d_ws layout (bf16 elements): wfb[3*16384] | y0 | y1 | y2
    __bf16* wfb = (__bf16*)d_ws;
    __bf16* y0  = wfb + 3 * 16384;
    __bf16* y1  = y0 + (size_t)2 * 65536 * 64;
    __bf16* y2  = y1 + (size_t)2 * 16384 * 64;

    wprep<<<24, 256, 0, stream>>>(W0, W1, W2, wfb);
    gemm_fused<<<5376, 256, 0, stream>>>(x0, x1, x2, wfb, y0, y1, y2);
    proj_fused<<<10240, 256, 0, stream>>>(y0, y1, y2, c0, c1, c2,
                                          nh0, nh1, nh2, oc,
                                          sig0, sig1, sig2,
                                          kap0, kap1, kap2, out);
}

// Round 12
// 112.611 us; speedup vs baseline: 1.0537x; 1.0537x over previous
//
#include <hip/hip_runtime.h>
#include <math.h>

#define PI_F        3.14159265358979323846f
#define TWO_PI_F    6.2831853071795864769f
#define INV_TWO_PI_F 0.15915494309189533577f

typedef __attribute__((ext_vector_type(8))) short  bf16x8;
typedef __attribute__((ext_vector_type(8))) __bf16 bf16v8;
typedef __attribute__((ext_vector_type(4))) float  f32x4;

__device__ __forceinline__ bf16x8 cvt8(f32x4 a, f32x4 b) {
    bf16v8 v;
    v[0] = (__bf16)a.x; v[1] = (__bf16)a.y; v[2] = (__bf16)a.z; v[3] = (__bf16)a.w;
    v[4] = (__bf16)b.x; v[5] = (__bf16)b.y; v[6] = (__bf16)b.z; v[7] = (__bf16)b.w;
    return __builtin_bit_cast(bf16x8, v);
}

__device__ __forceinline__ unsigned pk2(float lo, float hi) {
    unsigned short l = __builtin_bit_cast(unsigned short, (__bf16)lo);
    unsigned short h = __builtin_bit_cast(unsigned short, (__bf16)hi);
    return ((unsigned)h << 16) | (unsigned)l;
}

// ------------------------------------------------------------------
// W prep (unchanged): wfb[level][(nt4*8+ks)*64 + lane] =
//   W[nt4*16+(l&15)][ks*32+(l>>4)*8 ..+8] as bf16x8 fragments.
// ------------------------------------------------------------------
__global__ __launch_bounds__(256) void wprep(
    const float* __restrict__ W0, const float* __restrict__ W1,
    const float* __restrict__ W2, __bf16* __restrict__ wfb)
{
    const int level = blockIdx.x >> 3;
    const int rem   = ((blockIdx.x & 7) << 8) | threadIdx.x;   // 0..2047
    const float* W  = level == 0 ? W0 : (level == 1 ? W1 : W2);
    const int l   = rem & 63;
    const int ks  = (rem >> 6) & 7;
    const int nt4 = rem >> 9;
    const int col = nt4 * 16 + (l & 15);
    const int k0  = ks * 32 + (l >> 4) * 8;
    const float* wp = W + col * 256 + k0;
    bf16x8 f = cvt8(*(const f32x4*)wp, *(const f32x4*)(wp + 4));
    *(bf16x8*)(wfb + (size_t)level * 16384 + (size_t)rem * 8) = f;
}

// ------------------------------------------------------------------
// Persistent streaming bf16-MFMA GEMM: y = x (.) W^T, K=256, Do=64,
// y stored bf16. Each block processes 4 consecutive 32-row tiles; each
// wave owns 16 rows x 32 cols per tile. Register pipeline with inline-asm
// loads (can't be sunk) + counted vmcnt waits tied to the buffers:
//   steady state per tile: wait vmcnt(10) [A ready; st2+B8 younger],
//   compute kh0, issue A(t+1), wait vmcnt(8) [B ready; A'8 younger],
//   compute kh1, store (2x dwordx2), issue B(t+1).
// Swapped-operand MFMA: acc = mfma(wf, xfrag) -> C: x-row = lane&15,
// y-col = (lane>>4)*4+reg -> lane holds 4 consecutive y cols = 8B store.
// ------------------------------------------------------------------
#define GLD(dst, p, OFFSTR) \
    asm volatile("global_load_dwordx4 %0, %1, off offset:" OFFSTR \
                 : "=v"(dst) : "v"(p))

#define ISSUEA(p) \
    GLD(a0,p,"0");   GLD(a1,p,"16");  GLD(a2,p,"128"); GLD(a3,p,"144"); \
    GLD(a4,p,"256"); GLD(a5,p,"272"); GLD(a6,p,"384"); GLD(a7,p,"400")
#define ISSUEB(p) \
    GLD(b0,p,"512"); GLD(b1,p,"528"); GLD(b2,p,"640"); GLD(b3,p,"656"); \
    GLD(b4,p,"768"); GLD(b5,p,"784"); GLD(b6,p,"896"); GLD(b7,p,"912")

#define WAITA(NSTR) \
    asm volatile("s_waitcnt vmcnt(" NSTR ")" \
        : "+v"(a0),"+v"(a1),"+v"(a2),"+v"(a3), \
          "+v"(a4),"+v"(a5),"+v"(a6),"+v"(a7)); \
    __builtin_amdgcn_sched_barrier(0)
#define WAITB(NSTR) \
    asm volatile("s_waitcnt vmcnt(" NSTR ")" \
        : "+v"(b0),"+v"(b1),"+v"(b2),"+v"(b3), \
          "+v"(b4),"+v"(b5),"+v"(b6),"+v"(b7)); \
    __builtin_amdgcn_sched_barrier(0)

#define MFMA_(A,B,C) __builtin_amdgcn_mfma_f32_16x16x32_bf16(A,B,C,0,0,0)

#define COMPA() { bf16x8 f_; \
    f_ = cvt8(a0,a1); acc0 = MFMA_(wf0[0],f_,acc0); acc1 = MFMA_(wf1[0],f_,acc1); \
    f_ = cvt8(a2,a3); acc0 = MFMA_(wf0[1],f_,acc0); acc1 = MFMA_(wf1[1],f_,acc1); \
    f_ = cvt8(a4,a5); acc0 = MFMA_(wf0[2],f_,acc0); acc1 = MFMA_(wf1[2],f_,acc1); \
    f_ = cvt8(a6,a7); acc0 = MFMA_(wf0[3],f_,acc0); acc1 = MFMA_(wf1[3],f_,acc1); }
#define COMPB() { bf16x8 f_; \
    f_ = cvt8(b0,b1); acc0 = MFMA_(wf0[4],f_,acc0); acc1 = MFMA_(wf1[4],f_,acc1); \
    f_ = cvt8(b2,b3); acc0 = MFMA_(wf0[5],f_,acc0); acc1 = MFMA_(wf1[5],f_,acc1); \
    f_ = cvt8(b4,b5); acc0 = MFMA_(wf0[6],f_,acc0); acc1 = MFMA_(wf1[6],f_,acc1); \
    f_ = cvt8(b6,b7); acc0 = MFMA_(wf0[7],f_,acc0); acc1 = MFMA_(wf1[7],f_,acc1); }

#define STORE(yp) { \
    uint2 u0_, u1_; \
    u0_.x = pk2(acc0[0],acc0[1]); u0_.y = pk2(acc0[2],acc0[3]); \
    u1_.x = pk2(acc1[0],acc1[1]); u1_.y = pk2(acc1[2],acc1[3]); \
    asm volatile("global_store_dwordx2 %0, %1, off"           :: "v"(yp), "v"(u0_) : "memory"); \
    asm volatile("global_store_dwordx2 %0, %1, off offset:32" :: "v"(yp), "v"(u1_) : "memory"); \
    acc0 = f32x4{0.f,0.f,0.f,0.f}; acc1 = f32x4{0.f,0.f,0.f,0.f}; }

__device__ __forceinline__ void gemm_body(
    int bid,
    const float* __restrict__ x, const __bf16* __restrict__ wfb,
    __bf16* __restrict__ y)
{
    const int tid  = threadIdx.x;
    const int lane = tid & 63;
    const int w    = tid >> 6;
    const int wm   = w >> 1;                 // 16-row half within the 32-row tile
    const int wn   = w & 1;                  // 32-col half
    const int l16  = lane & 15;
    const int lq   = lane >> 4;

    // ---- W fragments (plain loads), then force the compiler's own
    // vmcnt wait HERE so it never inserts one inside the pipeline.
    bf16x8 wf0[8], wf1[8];
    {
        const __bf16* wb0 = wfb + (size_t)(wn * 2) * 4096 + (size_t)lane * 8;
        #pragma unroll
        for (int ks = 0; ks < 8; ++ks) {
            wf0[ks] = *(const bf16x8*)(wb0 + ks * 512);
            wf1[ks] = *(const bf16x8*)(wb0 + 4096 + ks * 512);
        }
    }
    asm volatile("" ::
        "v"(wf0[0]),"v"(wf0[1]),"v"(wf0[2]),"v"(wf0[3]),
        "v"(wf0[4]),"v"(wf0[5]),"v"(wf0[6]),"v"(wf0[7]),
        "v"(wf1[0]),"v"(wf1[1]),"v"(wf1[2]),"v"(wf1[3]),
        "v"(wf1[4]),"v"(wf1[5]),"v"(wf1[6]),"v"(wf1[7]));
    __builtin_amdgcn_sched_barrier(0);

    // ---- pointers for the 4 tiles this block owns
    const long row00 = (long)bid * 128 + wm * 16;         // tile 0 row base
    const float* xp0 = x + (row00 + l16) * 256 + lq * 8;
    const float* xp1 = xp0 + 32 * 256;
    const float* xp2 = xp1 + 32 * 256;
    const float* xp3 = xp2 + 32 * 256;
    __bf16* yp0 = y + (row00 + l16) * 64 + wn * 32 + lq * 4;
    __bf16* yp1 = yp0 + 32 * 64;
    __bf16* yp2 = yp1 + 32 * 64;
    __bf16* yp3 = yp2 + 32 * 64;

    f32x4 a0,a1,a2,a3,a4,a5,a6,a7;
    f32x4 b0,b1,b2,b3,b4,b5,b6,b7;
    f32x4 acc0 = {0.f,0.f,0.f,0.f}, acc1 = {0.f,0.f,0.f,0.f};

    // ---- prologue: fill both buffers for tile 0
    ISSUEA(xp0);
    ISSUEB(xp0);

    // ---- tile 0 (entry outstanding: A8,B8)
    WAITA("8");  COMPA();
    ISSUEA(xp1);
    WAITB("8");  COMPB();
    STORE(yp0);
    ISSUEB(xp1);
    // ---- tile 1 (entry: A8,st2,B8)
    WAITA("10"); COMPA();
    ISSUEA(xp2);
    WAITB("8");  COMPB();
    STORE(yp1);
    ISSUEB(xp2);
    // ---- tile 2
    WAITA("10"); COMPA();
    ISSUEA(xp3);
    WAITB("8");  COMPB();
    STORE(yp2);
    ISSUEB(xp3);
    // ---- tile 3 (no prefetch)
    WAITA("10"); COMPA();
    WAITB("0");  COMPB();
    STORE(yp3);
}

// Fused GEMM: blocks [0,1024) L0, [1024,1280) L1, [1280,1344) L2;
// each block = 4 consecutive 32-row tiles (128 rows).
__global__ __launch_bounds__(256, 3) void gemm_fused(
    const float* __restrict__ x0, const float* __restrict__ x1,
    const float* __restrict__ x2,
    const __bf16* __restrict__ wfb,
    __bf16* __restrict__ y0, __bf16* __restrict__ y1, __bf16* __restrict__ y2)
{
    const int b = blockIdx.x;
    if (b < 1024)       gemm_body(b,        x0, wfb,         y0);
    else if (b < 1280)  gemm_body(b - 1024, x1, wfb + 16384, y1);
    else                gemm_body(b - 1280, x2, wfb + 32768, y2);
}

// ------------------------------------------------------------------
// Projection body (unchanged): per group g, neighbors nh[g][0..7]:
//   logw[p][j] = -(dlat^2+dlon_w^2)/(2 sigma^2) + kappa*(cos(dlon_w)-1)
//   w = softmax_j(logw);  out[n=g*GS+p][d] = sum_j w[p][j]*y[nh[g][j]][d]
// ------------------------------------------------------------------
template<int GS, int CG, int ROUNDS>
__device__ __forceinline__ void proj_body(
    int bid, float (*wlds)[128],
    const __bf16* __restrict__ y,      // [B*N][64] bf16
    const float* __restrict__ coords,  // [2][N]
    const int*   __restrict__ nh,      // [N][8]
    const float* __restrict__ oc,      // [2][B][N0]
    const float* __restrict__ sig_p,
    const float* __restrict__ kap_p,
    float* __restrict__ out,           // [B][N0][64]
    int N, int N0)
{
    constexpr int B = 2;
    static_assert(CG * GS == ROUNDS * 8, "slot layout");

    const int wslot = threadIdx.x >> 6;
    const int lane  = threadIdx.x & 63;
    const int wave  = (bid << 2) + wslot;
    const int gpb   = N / CG;
    const int b     = wave / gpb;
    const int g0    = (wave - b * gpb) * CG;

    const float sigma  = *sig_p;
    const float kappa  = *kap_p;
    const float inv2s2 = 1.0f / (2.0f * sigma * sigma);

    const int j  = lane & 7;
    const int pp = lane >> 3;

    #pragma unroll
    for (int r = 0; r < ROUNDS; ++r) {
        const int pidx = r * 8 + pp;
        const int q = pidx / GS;
        const int p = pidx - q * GS;
        const int g = g0 + q;
        const int idx = nh[g * 8 + j];
        const float clon = coords[idx];
        const float clat = coords[N + idx];
        const int n = g * GS + p;
        const float olon = oc[(long)b * N0 + n];
        const float olat = oc[(long)(B + b) * N0 + n];

        float dlon = olon - clon;
        float t = (dlon + PI_F) * INV_TWO_PI_F;   // floor-mod wrap to [-pi, pi)
        t -= floorf(t);
        dlon = t * TWO_PI_F - PI_F;
        const float dlat = olat - clat;

        float logw = -(dlat * dlat + dlon * dlon) * inv2s2
                   + kappa * (cosf(dlon) - 1.0f);

        float m = logw;
        m = fmaxf(m, __shfl_xor(m, 1));
        m = fmaxf(m, __shfl_xor(m, 2));
        m = fmaxf(m, __shfl_xor(m, 4));
        float e = expf(logw - m);
        float s = e;
        s += __shfl_xor(s, 1);
        s += __shfl_xor(s, 2);
        s += __shfl_xor(s, 4);
        wlds[wslot][r * 64 + lane] = e / s;
    }

    __syncthreads();

    const int d = lane;
    const __bf16* yb = y + (long)b * N * 64 + d;
    #pragma unroll
    for (int pidx = 0; pidx < CG * GS; ++pidx) {
        const int q = pidx / GS;
        const int p = pidx - q * GS;
        const int g = g0 + q;
        const int* nhg = nh + g * 8;
        const float* wrow = &wlds[wslot][(pidx >> 3) * 64 + (pidx & 7) * 8];
        float a = 0.0f;
        #pragma unroll
        for (int jj = 0; jj < 8; ++jj)
            a = fmaf(wrow[jj], (float)yb[(long)nhg[jj] * 64], a);
        const int n = g * GS + p;
        out[((long)b * N0 + n) * 64 + d] = a;
    }
}

// Fused projection: blocks [0,4096) L0, [4096,8192) L1, [8192,10240) L2.
__global__ __launch_bounds__(256) void proj_fused(
    const __bf16* __restrict__ y0, const __bf16* __restrict__ y1,
    const __bf16* __restrict__ y2,
    const float* __restrict__ c0, const float* __restrict__ c1,
    const float* __restrict__ c2,
    const int* __restrict__ nh0, const int* __restrict__ nh1,
    const int* __restrict__ nh2,
    const float* __restrict__ oc,
    const float* __restrict__ sig0, const float* __restrict__ sig1,
    const float* __restrict__ sig2,
    const float* __restrict__ kap0, const float* __restrict__ kap1,
    const float* __restrict__ kap2,
    float* __restrict__ out)
{
    __shared__ float wlds[4][128];
    const size_t SLICE = (size_t)2 * 65536 * 64;
    const int b = blockIdx.x;
    if (b < 4096)
        proj_body<1, 8, 1>(b, wlds, y0, c0, nh0, oc, sig0, kap0,
                           out, 65536, 65536);
    else if (b < 8192)
        proj_body<4, 2, 1>(b - 4096, wlds, y1, c1, nh1, oc, sig1, kap1,
                           out + SLICE, 16384, 65536);
    else
        proj_body<16, 1, 2>(b - 8192, wlds, y2, c2, nh2, oc, sig2, kap2,
                            out + 2 * SLICE, 4096, 65536);
}

// ------------------------------------------------------------------
extern "C" void kernel_launch(void* const* d_in, const int* in_sizes, int n_in,
                              void* d_out, int out_size, void* d_ws, size_t ws_size,
                              hipStream_t stream)
{
    const float* x0   = (const float*)d_in[0];
    const float* x1   = (const float*)d_in[1];
    const float* x2   = (const float*)d_in[2];
    const float* W0   = (const float*)d_in[3];
    const float* W1   = (const float*)d_in[4];
    const float* W2   = (const float*)d_in[5];
    const float* sig0 = (const float*)d_in[6];
    const float* sig1 = (const float*)d_in[7];
    const float* sig2 = (const float*)d_in[8];
    const float* kap0 = (const float*)d_in[9];
    const float* kap1 = (const float*)d_in[10];
    const float* kap2 = (const float*)d_in[11];
    const float* c0   = (const float*)d_in[12];
    const float* c1   = (const float*)d_in[13];
    const float* c2   = (const float*)d_in[14];
    const int*   nh0  = (const int*)d_in[15];
    const int*   nh1  = (const int*)d_in[16];
    const int*   nh2  = (const int*)d_in[17];
    const float* oc   = (const float*)d_in[18];

    float* out = (float*)d_out;
    // d_ws layout (bf16 elements): wfb[3*16384] | y0 | y1 | y2
    __bf16* wfb = (__bf16*)d_ws;
    __bf16* y0  = wfb + 3 * 16384;
    __bf16* y1  = y0 + (size_t)2 * 65536 * 64;
    __bf16* y2  = y1 + (size_t)2 * 16384 * 64;

    wprep<<<24, 256, 0, stream>>>(W0, W1, W2, wfb);
    gemm_fused<<<1344, 256, 0, stream>>>(x0, x1, x2, wfb, y0, y1, y2);
    proj_fused<<<10240, 256, 0, stream>>>(y0, y1, y2, c0, c1, c2,
                                          nh0, nh1, nh2, oc,
                                          sig0, sig1, sig2,
                                          kap0, kap1, kap2, out);
}

// Round 13
// 93.327 us; speedup vs baseline: 1.2714x; 1.2066x over previous
//
#include <hip/hip_runtime.h>
#include <math.h>

#define PI_F        3.14159265358979323846f
#define TWO_PI_F    6.2831853071795864769f
#define INV_TWO_PI_F 0.15915494309189533577f

typedef __attribute__((ext_vector_type(8))) short  bf16x8;
typedef __attribute__((ext_vector_type(8))) __bf16 bf16v8;
typedef __attribute__((ext_vector_type(4))) float  f32x4;

__device__ __forceinline__ bf16x8 cvt8(f32x4 a, f32x4 b) {
    bf16v8 v;
    v[0] = (__bf16)a.x; v[1] = (__bf16)a.y; v[2] = (__bf16)a.z; v[3] = (__bf16)a.w;
    v[4] = (__bf16)b.x; v[5] = (__bf16)b.y; v[6] = (__bf16)b.z; v[7] = (__bf16)b.w;
    return __builtin_bit_cast(bf16x8, v);
}

__device__ __forceinline__ unsigned pk2(float lo, float hi) {
    unsigned short l = __builtin_bit_cast(unsigned short, (__bf16)lo);
    unsigned short h = __builtin_bit_cast(unsigned short, (__bf16)hi);
    return ((unsigned)h << 16) | (unsigned)l;
}

// ------------------------------------------------------------------
// W prep (unchanged): wfb[level][(nt4*8+ks)*64 + lane] =
//   W[nt4*16+(l&15)][ks*32+(l>>4)*8 ..+8] as bf16x8 fragments.
// ------------------------------------------------------------------
__global__ __launch_bounds__(256) void wprep(
    const float* __restrict__ W0, const float* __restrict__ W1,
    const float* __restrict__ W2, __bf16* __restrict__ wfb)
{
    const int level = blockIdx.x >> 3;
    const int rem   = ((blockIdx.x & 7) << 8) | threadIdx.x;   // 0..2047
    const float* W  = level == 0 ? W0 : (level == 1 ? W1 : W2);
    const int l   = rem & 63;
    const int ks  = (rem >> 6) & 7;
    const int nt4 = rem >> 9;
    const int col = nt4 * 16 + (l & 15);
    const int k0  = ks * 32 + (l >> 4) * 8;
    const float* wp = W + col * 256 + k0;
    bf16x8 f = cvt8(*(const f32x4*)wp, *(const f32x4*)(wp + 4));
    *(bf16x8*)(wfb + (size_t)level * 16384 + (size_t)rem * 8) = f;
}

// ------------------------------------------------------------------
// Persistent DMA-pipelined bf16-MFMA GEMM: y = x (.) W^T, K=256, Do=64,
// y stored bf16. Block = 256 thr (4 waves), owns 8 consecutive 16-row
// slabs (rows = bid*128..+127). LDS = 2 x 16KB slab buffers (32KB ->
// 5 blocks/CU). Per slab: each wave DMAs its own 4 rows (4 x 1KB
// global_load_lds, source 16B-chunk XOR pre-swizzle chunk^=(row&7)),
// waits counted vmcnt (next slab's DMAs + last store stay in flight),
// raw s_barrier (no vmcnt(0) drain!), 8 MFMAs, barrier, 1 store, issue
// slab+2. In-flight/CU = 5 blocks x 32KB, continuously refreshed.
// Swapped-operand MFMA: acc = mfma(wf, xfrag):
//   A = wf: col m = lane&15 (wave cols w*16..+15), k = ks*32+(lane>>4)*8
//   B = x:  row n = lane&15, same k  -> row-major 32B LDS read
//   C: n(row) = lane&15, m(col) = (lane>>4)*4+reg -> 4 consecutive y
//   cols per lane = one dwordx2 store after pk2.
// ------------------------------------------------------------------
#define WAITN(NSTR) \
    asm volatile("s_waitcnt vmcnt(" NSTR ")" ::: "memory"); \
    __builtin_amdgcn_sched_barrier(0); \
    __builtin_amdgcn_s_barrier(); \
    __builtin_amdgcn_sched_barrier(0)

#define BAR2 \
    __builtin_amdgcn_sched_barrier(0); \
    __builtin_amdgcn_s_barrier(); \
    __builtin_amdgcn_sched_barrier(0)

#define ISSUE_SLAB(BUF, SLAB) \
    { _Pragma("unroll") \
      for (int q = 0; q < 4; ++q) { \
          const int r_ = w * 4 + q; \
          const float* src_ = x + (rowbase + (SLAB) * 16 + r_) * 256 \
                                + ((lane ^ (r_ & 7)) << 2); \
          __builtin_amdgcn_global_load_lds( \
              (const __attribute__((address_space(1))) unsigned int*)src_, \
              (__attribute__((address_space(3))) unsigned int*) \
                  (lds + (BUF) * 4096 + r_ * 256), \
              16, 0, 0); \
      } }

#define COMPUTE(BUF) \
    { const float* base_ = lds + (BUF) * 4096 + l16 * 256; \
      _Pragma("unroll") \
      for (int ks = 0; ks < 8; ++ks) { \
          const int c0_ = ks * 8 + lq * 2; \
          f32x4 a0_ = *(const f32x4*)(base_ + (((c0_)     ^ sw) << 2)); \
          f32x4 a1_ = *(const f32x4*)(base_ + (((c0_ | 1) ^ sw) << 2)); \
          acc = __builtin_amdgcn_mfma_f32_16x16x32_bf16( \
                    wf[ks], cvt8(a0_, a1_), acc, 0, 0, 0); \
      } }

#define STOREY(SLAB) \
    { uint2 u_; u_.x = pk2(acc[0], acc[1]); u_.y = pk2(acc[2], acc[3]); \
      *(uint2*)(y + (rowbase + (SLAB) * 16 + l16) * 64 + w * 16 + lq * 4) = u_; \
      acc = f32x4{0.f, 0.f, 0.f, 0.f}; }

__device__ __forceinline__ void gemm_body(
    long rowbase, float* lds,          // [2][16][256] f32
    const float* __restrict__ x, const __bf16* __restrict__ wfb,
    __bf16* __restrict__ y)
{
    const int tid  = threadIdx.x;
    const int lane = tid & 63;
    const int w    = tid >> 6;
    const int l16  = lane & 15;
    const int lq   = lane >> 4;
    const int sw   = l16 & 7;

    // ---- W fragments: wave w owns cols w*16..w*16+15 (32 VGPR).
    // Consumer asm forces them resident (and drained) BEFORE any DMA.
    bf16x8 wf[8];
    {
        const __bf16* wb = wfb + (size_t)w * 4096 + (size_t)lane * 8;
        #pragma unroll
        for (int ks = 0; ks < 8; ++ks)
            wf[ks] = *(const bf16x8*)(wb + ks * 512);
    }
    asm volatile("" ::
        "v"(wf[0]), "v"(wf[1]), "v"(wf[2]), "v"(wf[3]),
        "v"(wf[4]), "v"(wf[5]), "v"(wf[6]), "v"(wf[7]));
    __builtin_amdgcn_sched_barrier(0);

    f32x4 acc = {0.f, 0.f, 0.f, 0.f};

    // ---- pipeline over 8 slabs, depth-2 prefetch, counted waits.
    ISSUE_SLAB(0, 0)
    ISSUE_SLAB(1, 1)
    WAITN("4"); COMPUTE(0) BAR2; STOREY(0) ISSUE_SLAB(0, 2)
    WAITN("5"); COMPUTE(1) BAR2; STOREY(1) ISSUE_SLAB(1, 3)
    WAITN("5"); COMPUTE(0) BAR2; STOREY(2) ISSUE_SLAB(0, 4)
    WAITN("5"); COMPUTE(1) BAR2; STOREY(3) ISSUE_SLAB(1, 5)
    WAITN("5"); COMPUTE(0) BAR2; STOREY(4) ISSUE_SLAB(0, 6)
    WAITN("5"); COMPUTE(1) BAR2; STOREY(5) ISSUE_SLAB(1, 7)
    WAITN("5"); COMPUTE(0) BAR2; STOREY(6)
    WAITN("0"); COMPUTE(1)       STOREY(7)
}

// Fused GEMM: blocks [0,1024) L0, [1024,1280) L1, [1280,1344) L2;
// each block = 8 consecutive 16-row slabs (128 rows).
__global__ __launch_bounds__(256) void gemm_fused(
    const float* __restrict__ x0, const float* __restrict__ x1,
    const float* __restrict__ x2,
    const __bf16* __restrict__ wfb,
    __bf16* __restrict__ y0, __bf16* __restrict__ y1, __bf16* __restrict__ y2)
{
    __shared__ float lds[2 * 4096];    // 32 KB
    const int b = blockIdx.x;
    if (b < 1024)       gemm_body((long)b * 128,          lds, x0, wfb,         y0);
    else if (b < 1280)  gemm_body((long)(b - 1024) * 128, lds, x1, wfb + 16384, y1);
    else                gemm_body((long)(b - 1280) * 128, lds, x2, wfb + 32768, y2);
}

// ------------------------------------------------------------------
// Projection body (unchanged): per group g, neighbors nh[g][0..7]:
//   logw[p][j] = -(dlat^2+dlon_w^2)/(2 sigma^2) + kappa*(cos(dlon_w)-1)
//   w = softmax_j(logw);  out[n=g*GS+p][d] = sum_j w[p][j]*y[nh[g][j]][d]
// ------------------------------------------------------------------
template<int GS, int CG, int ROUNDS>
__device__ __forceinline__ void proj_body(
    int bid, float (*wlds)[128],
    const __bf16* __restrict__ y,      // [B*N][64] bf16
    const float* __restrict__ coords,  // [2][N]
    const int*   __restrict__ nh,      // [N][8]
    const float* __restrict__ oc,      // [2][B][N0]
    const float* __restrict__ sig_p,
    const float* __restrict__ kap_p,
    float* __restrict__ out,           // [B][N0][64]
    int N, int N0)
{
    constexpr int B = 2;
    static_assert(CG * GS == ROUNDS * 8, "slot layout");

    const int wslot = threadIdx.x >> 6;
    const int lane  = threadIdx.x & 63;
    const int wave  = (bid << 2) + wslot;
    const int gpb   = N / CG;
    const int b     = wave / gpb;
    const int g0    = (wave - b * gpb) * CG;

    const float sigma  = *sig_p;
    const float kappa  = *kap_p;
    const float inv2s2 = 1.0f / (2.0f * sigma * sigma);

    const int j  = lane & 7;
    const int pp = lane >> 3;

    #pragma unroll
    for (int r = 0; r < ROUNDS; ++r) {
        const int pidx = r * 8 + pp;
        const int q = pidx / GS;
        const int p = pidx - q * GS;
        const int g = g0 + q;
        const int idx = nh[g * 8 + j];
        const float clon = coords[idx];
        const float clat = coords[N + idx];
        const int n = g * GS + p;
        const float olon = oc[(long)b * N0 + n];
        const float olat = oc[(long)(B + b) * N0 + n];

        float dlon = olon - clon;
        float t = (dlon + PI_F) * INV_TWO_PI_F;   // floor-mod wrap to [-pi, pi)
        t -= floorf(t);
        dlon = t * TWO_PI_F - PI_F;
        const float dlat = olat - clat;

        float logw = -(dlat * dlat + dlon * dlon) * inv2s2
                   + kappa * (cosf(dlon) - 1.0f);

        float m = logw;
        m = fmaxf(m, __shfl_xor(m, 1));
        m = fmaxf(m, __shfl_xor(m, 2));
        m = fmaxf(m, __shfl_xor(m, 4));
        float e = expf(logw - m);
        float s = e;
        s += __shfl_xor(s, 1);
        s += __shfl_xor(s, 2);
        s += __shfl_xor(s, 4);
        wlds[wslot][r * 64 + lane] = e / s;
    }

    __syncthreads();

    const int d = lane;
    const __bf16* yb = y + (long)b * N * 64 + d;
    #pragma unroll
    for (int pidx = 0; pidx < CG * GS; ++pidx) {
        const int q = pidx / GS;
        const int p = pidx - q * GS;
        const int g = g0 + q;
        const int* nhg = nh + g * 8;
        const float* wrow = &wlds[wslot][(pidx >> 3) * 64 + (pidx & 7) * 8];
        float a = 0.0f;
        #pragma unroll
        for (int jj = 0; jj < 8; ++jj)
            a = fmaf(wrow[jj], (float)yb[(long)nhg[jj] * 64], a);
        const int n = g * GS + p;
        out[((long)b * N0 + n) * 64 + d] = a;
    }
}

// Fused projection: blocks [0,4096) L0, [4096,8192) L1, [8192,10240) L2.
__global__ __launch_bounds__(256) void proj_fused(
    const __bf16* __restrict__ y0, const __bf16* __restrict__ y1,
    const __bf16* __restrict__ y2,
    const float* __restrict__ c0, const float* __restrict__ c1,
    const float* __restrict__ c2,
    const int* __restrict__ nh0, const int* __restrict__ nh1,
    const int* __restrict__ nh2,
    const float* __restrict__ oc,
    const float* __restrict__ sig0, const float* __restrict__ sig1,
    const float* __restrict__ sig2,
    const float* __restrict__ kap0, const float* __restrict__ kap1,
    const float* __restrict__ kap2,
    float* __restrict__ out)
{
    __shared__ float wlds[4][128];
    const size_t SLICE = (size_t)2 * 65536 * 64;
    const int b = blockIdx.x;
    if (b < 4096)
        proj_body<1, 8, 1>(b, wlds, y0, c0, nh0, oc, sig0, kap0,
                           out, 65536, 65536);
    else if (b < 8192)
        proj_body<4, 2, 1>(b - 4096, wlds, y1, c1, nh1, oc, sig1, kap1,
                           out + SLICE, 16384, 65536);
    else
        proj_body<16, 1, 2>(b - 8192, wlds, y2, c2, nh2, oc, sig2, kap2,
                            out + 2 * SLICE, 4096, 65536);
}

// ------------------------------------------------------------------
extern "C" void kernel_launch(void* const* d_in, const int* in_sizes, int n_in,
                              void* d_out, int out_size, void* d_ws, size_t ws_size,
                              hipStream_t stream)
{
    const float* x0   = (const float*)d_in[0];
    const float* x1   = (const float*)d_in[1];
    const float* x2   = (const float*)d_in[2];
    const float* W0   = (const float*)d_in[3];
    const float* W1   = (const float*)d_in[4];
    const float* W2   = (const float*)d_in[5];
    const float* sig0 = (const float*)d_in[6];
    const float* sig1 = (const float*)d_in[7];
    const float* sig2 = (const float*)d_in[8];
    const float* kap0 = (const float*)d_in[9];
    const float* kap1 = (const float*)d_in[10];
    const float* kap2 = (const float*)d_in[11];
    const float* c0   = (const float*)d_in[12];
    const float* c1   = (const float*)d_in[13];
    const float* c2   = (const float*)d_in[14];
    const int*   nh0  = (const int*)d_in[15];
    const int*   nh1  = (const int*)d_in[16];
    const int*   nh2  = (const int*)d_in[17];
    const float* oc   = (const float*)d_in[18];

    float* out = (float*)d_out;
    // d_ws layout (bf16 elements): wfb[3*16384] | y0 | y1 | y2
    __bf16* wfb = (__bf16*)d_ws;
    __bf16* y0  = wfb + 3 * 16384;
    __bf16* y1  = y0 + (size_t)2 * 65536 * 64;
    __bf16* y2  = y1 + (size_t)2 * 16384 * 64;

    wprep<<<24, 256, 0, stream>>>(W0, W1, W2, wfb);
    gemm_fused<<<1344, 256, 0, stream>>>(x0, x1, x2, wfb, y0, y1, y2);
    proj_fused<<<10240, 256, 0, stream>>>(y0, y1, y2, c0, c1, c2,
                                          nh0, nh1, nh2, oc,
                                          sig0, sig1, sig2,
                                          kap0, kap1, kap2, out);
}

// Round 14
// 93.253 us; speedup vs baseline: 1.2724x; 1.0008x over previous
//
#include <hip/hip_runtime.h>
#include <math.h>

#define PI_F        3.14159265358979323846f
#define TWO_PI_F    6.2831853071795864769f
#define INV_TWO_PI_F 0.15915494309189533577f

typedef __attribute__((ext_vector_type(8))) short  bf16x8;
typedef __attribute__((ext_vector_type(8))) __bf16 bf16v8;
typedef __attribute__((ext_vector_type(4))) float  f32x4;

__device__ __forceinline__ bf16x8 cvt8(f32x4 a, f32x4 b) {
    bf16v8 v;
    v[0] = (__bf16)a.x; v[1] = (__bf16)a.y; v[2] = (__bf16)a.z; v[3] = (__bf16)a.w;
    v[4] = (__bf16)b.x; v[5] = (__bf16)b.y; v[6] = (__bf16)b.z; v[7] = (__bf16)b.w;
    return __builtin_bit_cast(bf16x8, v);
}

__device__ __forceinline__ unsigned pk2(float lo, float hi) {
    unsigned short l = __builtin_bit_cast(unsigned short, (__bf16)lo);
    unsigned short h = __builtin_bit_cast(unsigned short, (__bf16)hi);
    return ((unsigned)h << 16) | (unsigned)l;
}

// ------------------------------------------------------------------
// W prep (unchanged): wfb[level][(nt4*8+ks)*64 + lane] =
//   W[nt4*16+(l&15)][ks*32+(l>>4)*8 ..+8] as bf16x8 fragments.
// ------------------------------------------------------------------
__global__ __launch_bounds__(256) void wprep(
    const float* __restrict__ W0, const float* __restrict__ W1,
    const float* __restrict__ W2, __bf16* __restrict__ wfb)
{
    const int level = blockIdx.x >> 3;
    const int rem   = ((blockIdx.x & 7) << 8) | threadIdx.x;   // 0..2047
    const float* W  = level == 0 ? W0 : (level == 1 ? W1 : W2);
    const int l   = rem & 63;
    const int ks  = (rem >> 6) & 7;
    const int nt4 = rem >> 9;
    const int col = nt4 * 16 + (l & 15);
    const int k0  = ks * 32 + (l >> 4) * 8;
    const float* wp = W + col * 256 + k0;
    bf16x8 f = cvt8(*(const f32x4*)wp, *(const f32x4*)(wp + 4));
    *(bf16x8*)(wfb + (size_t)level * 16384 + (size_t)rem * 8) = f;
}

// ------------------------------------------------------------------
// Persistent DMA-pipelined bf16-MFMA GEMM: y = x (.) W^T, K=256, Do=64,
// y stored bf16. Block = 256 thr (4 waves), owns 8 consecutive 16-row
// slabs (rows = bid*128..+127). LDS = 2 x 16KB slab buffers (32KB ->
// 5 blocks/CU). Per slab: each wave DMAs its own 4 rows (4 x 1KB
// global_load_lds, source 16B-chunk XOR pre-swizzle chunk^=(row&7)),
// waits counted vmcnt (next slab's DMAs + last store stay in flight),
// raw s_barrier (no vmcnt(0) drain!), 8 MFMAs, barrier, 1 store, issue
// slab+2. In-flight/CU = 5 blocks x 32KB, continuously refreshed.
// Swapped-operand MFMA: acc = mfma(wf, xfrag):
//   A = wf: col m = lane&15 (wave cols w*16..+15), k = ks*32+(lane>>4)*8
//   B = x:  row n = lane&15, same k  -> row-major 32B LDS read
//   C: n(row) = lane&15, m(col) = (lane>>4)*4+reg -> 4 consecutive y
//   cols per lane = one dwordx2 store after pk2.
// ------------------------------------------------------------------
#define WAITN(NSTR) \
    asm volatile("s_waitcnt vmcnt(" NSTR ")" ::: "memory"); \
    __builtin_amdgcn_sched_barrier(0); \
    __builtin_amdgcn_s_barrier(); \
    __builtin_amdgcn_sched_barrier(0)

#define BAR2 \
    __builtin_amdgcn_sched_barrier(0); \
    __builtin_amdgcn_s_barrier(); \
    __builtin_amdgcn_sched_barrier(0)

#define ISSUE_SLAB(BUF, SLAB) \
    { _Pragma("unroll") \
      for (int q = 0; q < 4; ++q) { \
          const int r_ = w * 4 + q; \
          const float* src_ = x + (rowbase + (SLAB) * 16 + r_) * 256 \
                                + ((lane ^ (r_ & 7)) << 2); \
          __builtin_amdgcn_global_load_lds( \
              (const __attribute__((address_space(1))) unsigned int*)src_, \
              (__attribute__((address_space(3))) unsigned int*) \
                  (lds + (BUF) * 4096 + r_ * 256), \
              16, 0, 0); \
      } }

#define COMPUTE(BUF) \
    { const float* base_ = lds + (BUF) * 4096 + l16 * 256; \
      _Pragma("unroll") \
      for (int ks = 0; ks < 8; ++ks) { \
          const int c0_ = ks * 8 + lq * 2; \
          f32x4 a0_ = *(const f32x4*)(base_ + (((c0_)     ^ sw) << 2)); \
          f32x4 a1_ = *(const f32x4*)(base_ + (((c0_ | 1) ^ sw) << 2)); \
          acc = __builtin_amdgcn_mfma_f32_16x16x32_bf16( \
                    wf[ks], cvt8(a0_, a1_), acc, 0, 0, 0); \
      } }

#define STOREY(SLAB) \
    { uint2 u_; u_.x = pk2(acc[0], acc[1]); u_.y = pk2(acc[2], acc[3]); \
      *(uint2*)(y + (rowbase + (SLAB) * 16 + l16) * 64 + w * 16 + lq * 4) = u_; \
      acc = f32x4{0.f, 0.f, 0.f, 0.f}; }

__device__ __forceinline__ void gemm_body(
    long rowbase, float* lds,          // [2][16][256] f32
    const float* __restrict__ x, const __bf16* __restrict__ wfb,
    __bf16* __restrict__ y)
{
    const int tid  = threadIdx.x;
    const int lane = tid & 63;
    const int w    = tid >> 6;
    const int l16  = lane & 15;
    const int lq   = lane >> 4;
    const int sw   = l16 & 7;

    // ---- W fragments: wave w owns cols w*16..w*16+15 (32 VGPR).
    // Consumer asm forces them resident (and drained) BEFORE any DMA.
    bf16x8 wf[8];
    {
        const __bf16* wb = wfb + (size_t)w * 4096 + (size_t)lane * 8;
        #pragma unroll
        for (int ks = 0; ks < 8; ++ks)
            wf[ks] = *(const bf16x8*)(wb + ks * 512);
    }
    asm volatile("" ::
        "v"(wf[0]), "v"(wf[1]), "v"(wf[2]), "v"(wf[3]),
        "v"(wf[4]), "v"(wf[5]), "v"(wf[6]), "v"(wf[7]));
    __builtin_amdgcn_sched_barrier(0);

    f32x4 acc = {0.f, 0.f, 0.f, 0.f};

    // ---- pipeline over 8 slabs, depth-2 prefetch, counted waits.
    ISSUE_SLAB(0, 0)
    ISSUE_SLAB(1, 1)
    WAITN("4"); COMPUTE(0) BAR2; STOREY(0) ISSUE_SLAB(0, 2)
    WAITN("5"); COMPUTE(1) BAR2; STOREY(1) ISSUE_SLAB(1, 3)
    WAITN("5"); COMPUTE(0) BAR2; STOREY(2) ISSUE_SLAB(0, 4)
    WAITN("5"); COMPUTE(1) BAR2; STOREY(3) ISSUE_SLAB(1, 5)
    WAITN("5"); COMPUTE(0) BAR2; STOREY(4) ISSUE_SLAB(0, 6)
    WAITN("5"); COMPUTE(1) BAR2; STOREY(5) ISSUE_SLAB(1, 7)
    WAITN("5"); COMPUTE(0) BAR2; STOREY(6)
    WAITN("0"); COMPUTE(1)       STOREY(7)
}

// Fused GEMM: blocks [0,1024) L0, [1024,1280) L1, [1280,1344) L2;
// each block = 8 consecutive 16-row slabs (128 rows).
__global__ __launch_bounds__(256) void gemm_fused(
    const float* __restrict__ x0, const float* __restrict__ x1,
    const float* __restrict__ x2,
    const __bf16* __restrict__ wfb,
    __bf16* __restrict__ y0, __bf16* __restrict__ y1, __bf16* __restrict__ y2)
{
    __shared__ float lds[2 * 4096];    // 32 KB
    const int b = blockIdx.x;
    if (b < 1024)       gemm_body((long)b * 128,          lds, x0, wfb,         y0);
    else if (b < 1280)  gemm_body((long)(b - 1024) * 128, lds, x1, wfb + 16384, y1);
    else                gemm_body((long)(b - 1280) * 128, lds, x2, wfb + 32768, y2);
}

// ------------------------------------------------------------------
// Projection body (unchanged): per group g, neighbors nh[g][0..7]:
//   logw[p][j] = -(dlat^2+dlon_w^2)/(2 sigma^2) + kappa*(cos(dlon_w)-1)
//   w = softmax_j(logw);  out[n=g*GS+p][d] = sum_j w[p][j]*y[nh[g][j]][d]
// ------------------------------------------------------------------
template<int GS, int CG, int ROUNDS>
__device__ __forceinline__ void proj_body(
    int bid, float (*wlds)[128],
    const __bf16* __restrict__ y,      // [B*N][64] bf16
    const float* __restrict__ coords,  // [2][N]
    const int*   __restrict__ nh,      // [N][8]
    const float* __restrict__ oc,      // [2][B][N0]
    const float* __restrict__ sig_p,
    const float* __restrict__ kap_p,
    float* __restrict__ out,           // [B][N0][64]
    int N, int N0)
{
    constexpr int B = 2;
    static_assert(CG * GS == ROUNDS * 8, "slot layout");

    const int wslot = threadIdx.x >> 6;
    const int lane  = threadIdx.x & 63;
    const int wave  = (bid << 2) + wslot;
    const int gpb   = N / CG;
    const int b     = wave / gpb;
    const int g0    = (wave - b * gpb) * CG;

    const float sigma  = *sig_p;
    const float kappa  = *kap_p;
    const float inv2s2 = 1.0f / (2.0f * sigma * sigma);

    const int j  = lane & 7;
    const int pp = lane >> 3;

    #pragma unroll
    for (int r = 0; r < ROUNDS; ++r) {
        const int pidx = r * 8 + pp;
        const int q = pidx / GS;
        const int p = pidx - q * GS;
        const int g = g0 + q;
        const int idx = nh[g * 8 + j];
        const float clon = coords[idx];
        const float clat = coords[N + idx];
        const int n = g * GS + p;
        const float olon = oc[(long)b * N0 + n];
        const float olat = oc[(long)(B + b) * N0 + n];

        float dlon = olon - clon;
        float t = (dlon + PI_F) * INV_TWO_PI_F;   // floor-mod wrap to [-pi, pi)
        t -= floorf(t);
        dlon = t * TWO_PI_F - PI_F;
        const float dlat = olat - clat;

        float logw = -(dlat * dlat + dlon * dlon) * inv2s2
                   + kappa * (cosf(dlon) - 1.0f);

        float m = logw;
        m = fmaxf(m, __shfl_xor(m, 1));
        m = fmaxf(m, __shfl_xor(m, 2));
        m = fmaxf(m, __shfl_xor(m, 4));
        float e = expf(logw - m);
        float s = e;
        s += __shfl_xor(s, 1);
        s += __shfl_xor(s, 2);
        s += __shfl_xor(s, 4);
        wlds[wslot][r * 64 + lane] = e / s;
    }

    __syncthreads();

    const int d = lane;
    const __bf16* yb = y + (long)b * N * 64 + d;
    #pragma unroll
    for (int pidx = 0; pidx < CG * GS; ++pidx) {
        const int q = pidx / GS;
        const int p = pidx - q * GS;
        const int g = g0 + q;
        const int* nhg = nh + g * 8;
        const float* wrow = &wlds[wslot][(pidx >> 3) * 64 + (pidx & 7) * 8];
        float a = 0.0f;
        #pragma unroll
        for (int jj = 0; jj < 8; ++jj)
            a = fmaf(wrow[jj], (float)yb[(long)nhg[jj] * 64], a);
        const int n = g * GS + p;
        out[((long)b * N0 + n) * 64 + d] = a;
    }
}

// Fused projection: blocks [0,4096) L0, [4096,8192) L1, [8192,10240) L2.
__global__ __launch_bounds__(256) void proj_fused(
    const __bf16* __restrict__ y0, const __bf16* __restrict__ y1,
    const __bf16* __restrict__ y2,
    const float* __restrict__ c0, const float* __restrict__ c1,
    const float* __restrict__ c2,
    const int* __restrict__ nh0, const int* __restrict__ nh1,
    const int* __restrict__ nh2,
    const float* __restrict__ oc,
    const float* __restrict__ sig0, const float* __restrict__ sig1,
    const float* __restrict__ sig2,
    const float* __restrict__ kap0, const float* __restrict__ kap1,
    const float* __restrict__ kap2,
    float* __restrict__ out)
{
    __shared__ float wlds[4][128];
    const size_t SLICE = (size_t)2 * 65536 * 64;
    const int b = blockIdx.x;
    if (b < 4096)
        proj_body<1, 8, 1>(b, wlds, y0, c0, nh0, oc, sig0, kap0,
                           out, 65536, 65536);
    else if (b < 8192)
        proj_body<4, 2, 1>(b - 4096, wlds, y1, c1, nh1, oc, sig1, kap1,
                           out + SLICE, 16384, 65536);
    else
        proj_body<16, 1, 2>(b - 8192, wlds, y2, c2, nh2, oc, sig2, kap2,
                            out + 2 * SLICE, 4096, 65536);
}

// ------------------------------------------------------------------
extern "C" void kernel_launch(void* const* d_in, const int* in_sizes, int n_in,
                              void* d_out, int out_size, void* d_ws, size_t ws_size,
                              hipStream_t stream)
{
    const float* x0   = (const float*)d_in[0];
    const float* x1   = (const float*)d_in[1];
    const float* x2   = (const float*)d_in[2];
    const float* W0   = (const float*)d_in[3];
    const float* W1   = (const float*)d_in[4];
    const float* W2   = (const float*)d_in[5];
    const float* sig0 = (const float*)d_in[6];
    const float* sig1 = (const float*)d_in[7];
    const float* sig2 = (const float*)d_in[8];
    const float* kap0 = (const float*)d_in[9];
    const float* kap1 = (const float*)d_in[10];
    const float* kap2 = (const float*)d_in[11];
    const float* c0   = (const float*)d_in[12];
    const float* c1   = (const float*)d_in[13];
    const float* c2   = (const float*)d_in[14];
    const int*   nh0  = (const int*)d_in[15];
    const int*   nh1  = (const int*)d_in[16];
    const int*   nh2  = (const int*)d_in[17];
    const float* oc   = (const float*)d_in[18];

    float* out = (float*)d_out;
    // d_ws layout (bf16 elements): wfb[3*16384] | y0 | y1 | y2
    __bf16* wfb = (__bf16*)d_ws;
    __bf16* y0  = wfb + 3 * 16384;
    __bf16* y1  = y0 + (size_t)2 * 65536 * 64;
    __bf16* y2  = y1 + (size_t)2 * 16384 * 64;

    wprep<<<24, 256, 0, stream>>>(W0, W1, W2, wfb);
    gemm_fused<<<1344, 256, 0, stream>>>(x0, x1, x2, wfb, y0, y1, y2);
    proj_fused<<<10240, 256, 0, stream>>>(y0, y1, y2, c0, c1, c2,
                                          nh0, nh1, nh2, oc,
                                          sig0, sig1, sig2,
                                          kap0, kap1, kap2, out);
}

// Round 15
// 87.998 us; speedup vs baseline: 1.3484x; 1.0597x over previous
//
#include <hip/hip_runtime.h>
#include <math.h>

#define PI_F        3.14159265358979323846f
#define TWO_PI_F    6.2831853071795864769f
#define INV_TWO_PI_F 0.15915494309189533577f

typedef __attribute__((ext_vector_type(8))) short  bf16x8;
typedef __attribute__((ext_vector_type(8))) __bf16 bf16v8;
typedef __attribute__((ext_vector_type(4))) float  f32x4;

__device__ __forceinline__ bf16x8 cvt8(f32x4 a, f32x4 b) {
    bf16v8 v;
    v[0] = (__bf16)a.x; v[1] = (__bf16)a.y; v[2] = (__bf16)a.z; v[3] = (__bf16)a.w;
    v[4] = (__bf16)b.x; v[5] = (__bf16)b.y; v[6] = (__bf16)b.z; v[7] = (__bf16)b.w;
    return __builtin_bit_cast(bf16x8, v);
}

__device__ __forceinline__ unsigned pk2(float lo, float hi) {
    unsigned short l = __builtin_bit_cast(unsigned short, (__bf16)lo);
    unsigned short h = __builtin_bit_cast(unsigned short, (__bf16)hi);
    return ((unsigned)h << 16) | (unsigned)l;
}

// ------------------------------------------------------------------
// W prep (unchanged): wfb[level][(nt4*8+ks)*64 + lane] =
//   W[nt4*16+(l&15)][ks*32+(l>>4)*8 ..+8] as bf16x8 fragments.
// ------------------------------------------------------------------
__global__ __launch_bounds__(256) void wprep(
    const float* __restrict__ W0, const float* __restrict__ W1,
    const float* __restrict__ W2, __bf16* __restrict__ wfb)
{
    const int level = blockIdx.x >> 3;
    const int rem   = ((blockIdx.x & 7) << 8) | threadIdx.x;   // 0..2047
    const float* W  = level == 0 ? W0 : (level == 1 ? W1 : W2);
    const int l   = rem & 63;
    const int ks  = (rem >> 6) & 7;
    const int nt4 = rem >> 9;
    const int col = nt4 * 16 + (l & 15);
    const int k0  = ks * 32 + (l >> 4) * 8;
    const float* wp = W + col * 256 + k0;
    bf16x8 f = cvt8(*(const f32x4*)wp, *(const f32x4*)(wp + 4));
    *(bf16x8*)(wfb + (size_t)level * 16384 + (size_t)rem * 8) = f;
}

// ------------------------------------------------------------------
// Persistent depth-3 DMA-pipelined bf16-MFMA GEMM: y = x (.) W^T,
// K=256, Do=64, y bf16. Block = 4 waves, owns 16 consecutive 16-row
// slabs (256 rows). LDS = 3 x 16KB slab buffers (48KB -> 3 blocks/CU;
// grid 672 fully co-resident, zero tail). Per slab: each wave DMAs its
// 4 rows (4 x global_load_lds, source 16B-chunk XOR pre-swizzle
// chunk^=(row&7)), counted vmcnt (2 future slabs' DMAs + 2 stores stay
// in flight -> steady wait vmcnt(10)), raw s_barrier (no drain),
// 8 MFMAs, barrier, 1 store, issue slab+3.
// Swapped-operand MFMA: acc = mfma(wf, xfrag):
//   A = wf: col m = lane&15 (wave cols w*16..+15), k = ks*32+(lane>>4)*8
//   B = x:  row n = lane&15, same k  -> row-major 32B LDS read
//   C: n(row) = lane&15, m(col) = (lane>>4)*4+reg -> one dwordx2 store.
// ------------------------------------------------------------------
#define WAITN(NSTR) \
    asm volatile("s_waitcnt vmcnt(" NSTR ")" ::: "memory"); \
    __builtin_amdgcn_sched_barrier(0); \
    __builtin_amdgcn_s_barrier(); \
    __builtin_amdgcn_sched_barrier(0)

#define BAR2 \
    __builtin_amdgcn_sched_barrier(0); \
    __builtin_amdgcn_s_barrier(); \
    __builtin_amdgcn_sched_barrier(0)

#define ISSUE_SLAB(BUF, SLAB) \
    { _Pragma("unroll") \
      for (int q = 0; q < 4; ++q) { \
          const int r_ = w * 4 + q; \
          const float* src_ = x + (rowbase + (long)(SLAB) * 16 + r_) * 256 \
                                + ((lane ^ (r_ & 7)) << 2); \
          __builtin_amdgcn_global_load_lds( \
              (const __attribute__((address_space(1))) unsigned int*)src_, \
              (__attribute__((address_space(3))) unsigned int*) \
                  (lds + (BUF) * 4096 + r_ * 256), \
              16, 0, 0); \
      } }

#define COMPUTE(BUF) \
    { const float* base_ = lds + (BUF) * 4096 + l16 * 256; \
      _Pragma("unroll") \
      for (int ks = 0; ks < 8; ++ks) { \
          const int c0_ = ks * 8 + lq * 2; \
          f32x4 a0_ = *(const f32x4*)(base_ + (((c0_)     ^ sw) << 2)); \
          f32x4 a1_ = *(const f32x4*)(base_ + (((c0_ | 1) ^ sw) << 2)); \
          acc = __builtin_amdgcn_mfma_f32_16x16x32_bf16( \
                    wf[ks], cvt8(a0_, a1_), acc, 0, 0, 0); \
      } }

#define STOREY(SLAB) \
    { uint2 u_; u_.x = pk2(acc[0], acc[1]); u_.y = pk2(acc[2], acc[3]); \
      *(uint2*)(y + (rowbase + (long)(SLAB) * 16 + l16) * 64 + w * 16 + lq * 4) = u_; \
      acc = f32x4{0.f, 0.f, 0.f, 0.f}; }

__device__ __forceinline__ void gemm_body(
    long rowbase, float* lds,          // [3][16][256] f32
    const float* __restrict__ x, const __bf16* __restrict__ wfb,
    __bf16* __restrict__ y)
{
    constexpr int NS = 16;             // slabs per block
    const int tid  = threadIdx.x;
    const int lane = tid & 63;
    const int w    = tid >> 6;
    const int l16  = lane & 15;
    const int lq   = lane >> 4;
    const int sw   = l16 & 7;

    // ---- W fragments: wave w owns cols w*16..w*16+15 (32 VGPR).
    // Consumer asm forces them resident (drained) BEFORE any DMA.
    bf16x8 wf[8];
    {
        const __bf16* wb = wfb + (size_t)w * 4096 + (size_t)lane * 8;
        #pragma unroll
        for (int ks = 0; ks < 8; ++ks)
            wf[ks] = *(const bf16x8*)(wb + ks * 512);
    }
    asm volatile("" ::
        "v"(wf[0]), "v"(wf[1]), "v"(wf[2]), "v"(wf[3]),
        "v"(wf[4]), "v"(wf[5]), "v"(wf[6]), "v"(wf[7]));
    __builtin_amdgcn_sched_barrier(0);

    f32x4 acc = {0.f, 0.f, 0.f, 0.f};

    // ---- prologue: 3 slabs in flight
    ISSUE_SLAB(0, 0)
    ISSUE_SLAB(1, 1)
    ISSUE_SLAB(2, 2)

    // iter 0: outstanding [s0x4,s1x4,s2x4]=12 -> need s0 -> <=8
    WAITN("8");  COMPUTE(0) BAR2; STOREY(0) ISSUE_SLAB(0, 3)
    // iter 1: [s1x4,s2x4,st0,s3x4]=13 -> need s1 -> <=9
    WAITN("9");  COMPUTE(1) BAR2; STOREY(1) ISSUE_SLAB(1, 4)
    // steady iters s=2..NS-4: entry 14-15, need slab s -> <=10
    {
        int buf = 2;
        #pragma unroll 1
        for (int s = 2; s <= NS - 4; ++s) {
            WAITN("10"); COMPUTE(buf) BAR2; STOREY(s) ISSUE_SLAB(buf, s + 3)
            buf = (buf == 2) ? 0 : buf + 1;
        }
    }
    // s = NS-3 (13, buf 1): entry 15, need s -> <=10; no issue
    WAITN("10"); COMPUTE(1) BAR2; STOREY(NS - 3)
    // s = NS-2 (14, buf 2): entry [st,4,st,4,st]=11 -> need slab -> <=6
    WAITN("6");  COMPUTE(2) BAR2; STOREY(NS - 2)
    // s = NS-1 (15, buf 0): entry 7 -> need slab -> <=2
    WAITN("2");  COMPUTE(0)       STOREY(NS - 1)
}

// Fused GEMM: blocks [0,512) L0, [512,640) L1, [640,672) L2;
// each block = 16 slabs (256 rows). 672 blocks all co-resident.
__global__ __launch_bounds__(256) void gemm_fused(
    const float* __restrict__ x0, const float* __restrict__ x1,
    const float* __restrict__ x2,
    const __bf16* __restrict__ wfb,
    __bf16* __restrict__ y0, __bf16* __restrict__ y1, __bf16* __restrict__ y2)
{
    __shared__ float lds[3 * 4096];    // 48 KB -> 3 blocks/CU
    const int b = blockIdx.x;
    if (b < 512)       gemm_body((long)b * 256,         lds, x0, wfb,         y0);
    else if (b < 640)  gemm_body((long)(b - 512) * 256, lds, x1, wfb + 16384, y1);
    else               gemm_body((long)(b - 640) * 256, lds, x2, wfb + 32768, y2);
}

// ------------------------------------------------------------------
// Projection body: per group g, neighbors nh[g][0..7]:
//   logw[p][j] = -(dlat^2+dlon_w^2)/(2 sigma^2) + kappa*(cos(dlon_w)-1)
//   w = softmax_j(logw);  out[n=g*GS+p][d] = sum_j w[p][j]*y[nh[g][j]][d]
// wlds is strictly per-wave (wslot) -> NO block barrier needed; the
// compiler's lgkmcnt tracking orders the same-wave LDS write->read.
// ------------------------------------------------------------------
template<int GS, int CG, int ROUNDS>
__device__ __forceinline__ void proj_body(
    int bid, float (*wlds)[128],
    const __bf16* __restrict__ y,      // [B*N][64] bf16
    const float* __restrict__ coords,  // [2][N]
    const int*   __restrict__ nh,      // [N][8]
    const float* __restrict__ oc,      // [2][B][N0]
    const float* __restrict__ sig_p,
    const float* __restrict__ kap_p,
    float* __restrict__ out,           // [B][N0][64]
    int N, int N0)
{
    constexpr int B = 2;
    static_assert(CG * GS == ROUNDS * 8, "slot layout");

    const int wslot = threadIdx.x >> 6;
    const int lane  = threadIdx.x & 63;
    const int wave  = (bid << 2) + wslot;
    const int gpb   = N / CG;
    const int b     = wave / gpb;
    const int g0    = (wave - b * gpb) * CG;

    const float sigma  = *sig_p;
    const float kappa  = *kap_p;
    const float inv2s2 = 1.0f / (2.0f * sigma * sigma);

    const int j  = lane & 7;
    const int pp = lane >> 3;

    #pragma unroll
    for (int r = 0; r < ROUNDS; ++r) {
        const int pidx = r * 8 + pp;
        const int q = pidx / GS;
        const int p = pidx - q * GS;
        const int g = g0 + q;
        const int idx = nh[g * 8 + j];
        const float clon = coords[idx];
        const float clat = coords[N + idx];
        const int n = g * GS + p;
        const float olon = oc[(long)b * N0 + n];
        const float olat = oc[(long)(B + b) * N0 + n];

        float dlon = olon - clon;
        float t = (dlon + PI_F) * INV_TWO_PI_F;   // floor-mod wrap to [-pi, pi)
        t -= floorf(t);
        dlon = t * TWO_PI_F - PI_F;
        const float dlat = olat - clat;

        float logw = -(dlat * dlat + dlon * dlon) * inv2s2
                   + kappa * (cosf(dlon) - 1.0f);

        float m = logw;
        m = fmaxf(m, __shfl_xor(m, 1));
        m = fmaxf(m, __shfl_xor(m, 2));
        m = fmaxf(m, __shfl_xor(m, 4));
        float e = expf(logw - m);
        float s = e;
        s += __shfl_xor(s, 1);
        s += __shfl_xor(s, 2);
        s += __shfl_xor(s, 4);
        wlds[wslot][r * 64 + lane] = e / s;
    }

    // no __syncthreads(): wlds[wslot] is same-wave data only.

    const int d = lane;
    const __bf16* yb = y + (long)b * N * 64 + d;
    #pragma unroll
    for (int pidx = 0; pidx < CG * GS; ++pidx) {
        const int q = pidx / GS;
        const int p = pidx - q * GS;
        const int g = g0 + q;
        const int* nhg = nh + g * 8;
        const float* wrow = &wlds[wslot][(pidx >> 3) * 64 + (pidx & 7) * 8];
        float a = 0.0f;
        #pragma unroll
        for (int jj = 0; jj < 8; ++jj)
            a = fmaf(wrow[jj], (float)yb[(long)nhg[jj] * 64], a);
        const int n = g * GS + p;
        out[((long)b * N0 + n) * 64 + d] = a;
    }
}

// Fused projection: blocks [0,4096) L0, [4096,8192) L1, [8192,10240) L2.
__global__ __launch_bounds__(256) void proj_fused(
    const __bf16* __restrict__ y0, const __bf16* __restrict__ y1,
    const __bf16* __restrict__ y2,
    const float* __restrict__ c0, const float* __restrict__ c1,
    const float* __restrict__ c2,
    const int* __restrict__ nh0, const int* __restrict__ nh1,
    const int* __restrict__ nh2,
    const float* __restrict__ oc,
    const float* __restrict__ sig0, const float* __restrict__ sig1,
    const float* __restrict__ sig2,
    const float* __restrict__ kap0, const float* __restrict__ kap1,
    const float* __restrict__ kap2,
    float* __restrict__ out)
{
    __shared__ float wlds[4][128];
    const size_t SLICE = (size_t)2 * 65536 * 64;
    const int b = blockIdx.x;
    if (b < 4096)
        proj_body<1, 8, 1>(b, wlds, y0, c0, nh0, oc, sig0, kap0,
                           out, 65536, 65536);
    else if (b < 8192)
        proj_body<4, 2, 1>(b - 4096, wlds, y1, c1, nh1, oc, sig1, kap1,
                           out + SLICE, 16384, 65536);
    else
        proj_body<16, 1, 2>(b - 8192, wlds, y2, c2, nh2, oc, sig2, kap2,
                            out + 2 * SLICE, 4096, 65536);
}

// ------------------------------------------------------------------
extern "C" void kernel_launch(void* const* d_in, const int* in_sizes, int n_in,
                              void* d_out, int out_size, void* d_ws, size_t ws_size,
                              hipStream_t stream)
{
    const float* x0   = (const float*)d_in[0];
    const float* x1   = (const float*)d_in[1];
    const float* x2   = (const float*)d_in[2];
    const float* W0   = (const float*)d_in[3];
    const float* W1   = (const float*)d_in[4];
    const float* W2   = (const float*)d_in[5];
    const float* sig0 = (const float*)d_in[6];
    const float* sig1 = (const float*)d_in[7];
    const float* sig2 = (const float*)d_in[8];
    const float* kap0 = (const float*)d_in[9];
    const float* kap1 = (const float*)d_in[10];
    const float* kap2 = (const float*)d_in[11];
    const float* c0   = (const float*)d_in[12];
    const float* c1   = (const float*)d_in[13];
    const float* c2   = (const float*)d_in[14];
    const int*   nh0  = (const int*)d_in[15];
    const int*   nh1  = (const int*)d_in[16];
    const int*   nh2  = (const int*)d_in[17];
    const float* oc   = (const float*)d_in[18];

    float* out = (float*)d_out;
    // d_ws layout (bf16 elements): wfb[3*16384] | y0 | y1 | y2
    __bf16* wfb = (__bf16*)d_ws;
    __bf16* y0  = wfb + 3 * 16384;
    __bf16* y1  = y0 + (size_t)2 * 65536 * 64;
    __bf16* y2  = y1 + (size_t)2 * 16384 * 64;

    wprep<<<24, 256, 0, stream>>>(W0, W1, W2, wfb);
    gemm_fused<<<672, 256, 0, stream>>>(x0, x1, x2, wfb, y0, y1, y2);
    proj_fused<<<10240, 256, 0, stream>>>(y0, y1, y2, c0, c1, c2,
                                          nh0, nh1, nh2, oc,
                                          sig0, sig1, sig2,
                                          kap0, kap1, kap2, out);
}